// Round 4
// baseline (280.786 us; speedup 1.0000x reference)
//
#include <hip/hip_runtime.h>
#include <hip/hip_bf16.h>

// Problem constants (reference: B,S,D,K = 4, 8192, 512, 20)
#define BB 4
#define SS 8192
#define DD 512
#define KK 20

__device__ __forceinline__ float dot4(float4 a, float4 b) {
  return a.x * b.x + a.y * b.y + a.z * b.z + a.w * b.w;
}

// ---------------------------------------------------------------------------
// k0: params[k]=||c_k||^2, params[K+k]=0.5/sigma^2, params[2K+k]=amp
// ---------------------------------------------------------------------------
__global__ void k0_params(const float* __restrict__ pos,
                          const float* __restrict__ log_scales,
                          const float* __restrict__ amps,
                          float* __restrict__ params) {
  int k = blockIdx.x;
  int lane = threadIdx.x;
  float acc = 0.f;
  for (int d = lane; d < DD; d += 64) { float p = pos[k * DD + d]; acc += p * p; }
#pragma unroll
  for (int off = 32; off > 0; off >>= 1) acc += __shfl_xor(acc, off);
  if (lane == 0) {
    params[k] = acc;
    float s = __expf(log_scales[k]);
    params[KK + k] = 0.5f / (s * s);
    params[2 * KK + k] = amps[k];
  }
}

// ---------------------------------------------------------------------------
// kA: attn. 1024 blocks x 256 thr; 32 tokens/block; 16 lanes/token;
// 2 tokens/thread (amortizes pos LDS reads). LDS = 40KB -> 4 blocks/CU.
// ---------------------------------------------------------------------------
__global__ __launch_bounds__(256) void kA_attn(
    const float* __restrict__ x, const float* __restrict__ pos,
    const float* __restrict__ params, float* __restrict__ attn_g) {
  __shared__ float pos_s[KK * DD];   // 40 KB
  __shared__ float prm_s[3 * KK];
  int tid = threadIdx.x;
  for (int i = tid; i < KK * DD / 4; i += 256)
    ((float4*)pos_s)[i] = ((const float4*)pos)[i];
  if (tid < 3 * KK) prm_s[tid] = params[tid];
  __syncthreads();

  int b = blockIdx.x >> 8;           // 256 chunks per batch
  int c = blockIdx.x & 255;
  size_t row0 = (size_t)b * SS + (size_t)c * 32;
  int g = tid >> 4;                  // token group 0..15
  int dsub = tid & 15;

  const float* xA = x + (row0 + g) * DD;
  const float* xB = xA + 16 * DD;

  float accA[KK], accB[KK], x2A = 0.f, x2B = 0.f;
#pragma unroll
  for (int k = 0; k < KK; ++k) { accA[k] = 0.f; accB[k] = 0.f; }

#pragma unroll 2
  for (int j = 0; j < 8; ++j) {
    int d0 = j * 64 + dsub * 4;
    float4 xa = *(const float4*)(xA + d0);
    float4 xb = *(const float4*)(xB + d0);
    x2A += dot4(xa, xa);
    x2B += dot4(xb, xb);
#pragma unroll
    for (int k = 0; k < KK; ++k) {
      float4 p = *(const float4*)(pos_s + k * DD + d0);
      accA[k] += dot4(xa, p);
      accB[k] += dot4(xb, p);
    }
  }

  // butterfly over the 16 lanes of each token group
#pragma unroll
  for (int m = 1; m <= 8; m <<= 1) { x2A += __shfl_xor(x2A, m); x2B += __shfl_xor(x2B, m); }
#pragma unroll
  for (int k = 0; k < KK; ++k) {
#pragma unroll
    for (int m = 1; m <= 8; m <<= 1) {
      accA[k] += __shfl_xor(accA[k], m);
      accB[k] += __shfl_xor(accB[k], m);
    }
  }

  if (dsub == 0) {
    float gg[KK];
    float sum = 0.f;
#pragma unroll
    for (int k = 0; k < KK; ++k) {
      float d2 = fmaxf(x2A - 2.f * accA[k] + prm_s[k], 0.f);
      gg[k] = prm_s[2 * KK + k] * __expf(-prm_s[KK + k] * d2);
      sum += gg[k];
    }
    float inv = 1.f / (sum + 1e-8f);
    float* ar = attn_g + (row0 + g) * KK;
#pragma unroll
    for (int k = 0; k < KK; ++k) ar[k] = gg[k] * inv;

    sum = 0.f;
#pragma unroll
    for (int k = 0; k < KK; ++k) {
      float d2 = fmaxf(x2B - 2.f * accB[k] + prm_s[k], 0.f);
      gg[k] = prm_s[2 * KK + k] * __expf(-prm_s[KK + k] * d2);
      sum += gg[k];
    }
    inv = 1.f / (sum + 1e-8f);
    ar = attn_g + (row0 + g + 16) * KK;
#pragma unroll
    for (int k = 0; k < KK; ++k) ar[k] = gg[k] * inv;
  }
}

// ---------------------------------------------------------------------------
// kB: Mpart[b,c,k,d] = sum_{s in chunk} attn[s,k]*x[s,d].
// grid (cpb, BB) x 256 thr; thread owns float2 d-slot; no LDS -> high occ.
// ---------------------------------------------------------------------------
__global__ __launch_bounds__(256) void kB_scatter(
    const float* __restrict__ x, const float* __restrict__ attn,
    float* __restrict__ Mpart, int tpc) {
  int t = threadIdx.x;
  int c = blockIdx.x;
  int b = blockIdx.y;
  int cpb = gridDim.x;
  size_t row0 = (size_t)b * SS + (size_t)c * tpc;

  float2 Ml[KK];
#pragma unroll
  for (int k = 0; k < KK; ++k) Ml[k] = make_float2(0.f, 0.f);

  const float* xb = x + row0 * DD + 2 * t;
  const float* ab = attn + row0 * KK;
  for (int s = 0; s < tpc; ++s) {
    float2 xv = *(const float2*)(xb + (size_t)s * DD);
    const float4* ar4 = (const float4*)(ab + s * KK);
#pragma unroll
    for (int kk = 0; kk < KK / 4; ++kk) {
      float4 a4 = ar4[kk];
      Ml[4 * kk + 0].x += a4.x * xv.x; Ml[4 * kk + 0].y += a4.x * xv.y;
      Ml[4 * kk + 1].x += a4.y * xv.x; Ml[4 * kk + 1].y += a4.y * xv.y;
      Ml[4 * kk + 2].x += a4.z * xv.x; Ml[4 * kk + 2].y += a4.z * xv.y;
      Ml[4 * kk + 3].x += a4.w * xv.x; Ml[4 * kk + 3].y += a4.w * xv.y;
    }
  }
  float* mp = Mpart + ((size_t)b * cpb + c) * KK * DD + 2 * t;
#pragma unroll
  for (int k = 0; k < KK; ++k) *(float2*)(mp + (size_t)k * DD) = Ml[k];
}

// ---------------------------------------------------------------------------
// k3f: chunk-reduce + proj_v + proj_o fused. 80 blocks x 512 thr.
// ---------------------------------------------------------------------------
__global__ __launch_bounds__(512) void k3f(
    const float* __restrict__ Mpart, const float* __restrict__ w_v,
    const float* __restrict__ w_o, float* __restrict__ ws2, int cpb) {
  __shared__ float m_s[DD];
  __shared__ float v_s[DD];
  int bk = blockIdx.x;
  int b = bk / KK, k = bk - b * KK;
  int e = threadIdx.x;

  const float* mp = Mpart + ((size_t)b * cpb) * KK * DD + (size_t)k * DD + e;
  float acc = 0.f;
#pragma unroll 8
  for (int c = 0; c < cpb; ++c) acc += mp[(size_t)c * KK * DD];
  m_s[e] = acc;
  __syncthreads();

  const float4* wr = (const float4*)(w_v + (size_t)e * DD);
  float a2 = 0.f;
#pragma unroll 4
  for (int j = 0; j < DD / 4; ++j) a2 += dot4(((const float4*)m_s)[j], wr[j]);
  v_s[e] = a2;
  __syncthreads();

  const float4* wr2 = (const float4*)(w_o + (size_t)e * DD);
  float a3 = 0.f;
#pragma unroll 4
  for (int j = 0; j < DD / 4; ++j) a3 += dot4(((const float4*)v_s)[j], wr2[j]);
  ws2[(size_t)bk * DD + e] = a3;
}

// ---------------------------------------------------------------------------
// k5: out[b,s,:] = sum_k attn[b,s,k]*ws2[b,k,:]. 2048 blocks x 256 thr.
// Thread owns float4 e-slot (20 w-float4 in regs); 2 token rows in flight;
// 16B coalesced stores (lanes 0..127 cover one full 2KB row).
// ---------------------------------------------------------------------------
__global__ __launch_bounds__(256) void k5_gather(
    const float* __restrict__ attn, const float* __restrict__ ws2,
    float* __restrict__ out) {
  int tid = threadIdx.x;
  int b = blockIdx.x >> 9;           // 512 chunks per batch
  int sc = blockIdx.x & 511;
  size_t s0 = (size_t)sc * 16;
  int tr = tid >> 7;                 // 0/1: which of two token rows
  int e4 = tid & 127;                // float4 column slot

  float4 w[KK];
  const float* wb = ws2 + (size_t)b * KK * DD + e4 * 4;
#pragma unroll
  for (int k = 0; k < KK; ++k) w[k] = *(const float4*)(wb + (size_t)k * DD);

  size_t rowA = (size_t)b * SS + s0 + tr;
  const float* ar = attn + rowA * KK;
  float* orow = out + rowA * DD + e4 * 4;

#pragma unroll 2
  for (int i = 0; i < 8; ++i) {
    const float4* a4 = (const float4*)(ar + (size_t)2 * i * KK);
    float4 A = a4[0], Bv = a4[1], C = a4[2], Dv = a4[3], E = a4[4];
    float4 o = make_float4(0.f, 0.f, 0.f, 0.f);
#define ACC(av, kbase) \
    o.x += av * w[kbase].x; o.y += av * w[kbase].y; \
    o.z += av * w[kbase].z; o.w += av * w[kbase].w;
    ACC(A.x, 0)  ACC(A.y, 1)  ACC(A.z, 2)  ACC(A.w, 3)
    ACC(Bv.x, 4) ACC(Bv.y, 5) ACC(Bv.z, 6) ACC(Bv.w, 7)
    ACC(C.x, 8)  ACC(C.y, 9)  ACC(C.z, 10) ACC(C.w, 11)
    ACC(Dv.x, 12) ACC(Dv.y, 13) ACC(Dv.z, 14) ACC(Dv.w, 15)
    ACC(E.x, 16) ACC(E.y, 17) ACC(E.z, 18) ACC(E.w, 19)
#undef ACC
    *(float4*)(orow + (size_t)2 * i * DD) = o;
  }
}

// ---------------------------------------------------------------------------
extern "C" void kernel_launch(void* const* d_in, const int* in_sizes, int n_in,
                              void* d_out, int out_size, void* d_ws, size_t ws_size,
                              hipStream_t stream) {
  const float* x   = (const float*)d_in[0];
  const float* pos = (const float*)d_in[1];
  const float* ls  = (const float*)d_in[2];
  const float* am  = (const float*)d_in[3];
  const float* w_v = (const float*)d_in[4];
  const float* w_o = (const float*)d_in[5];
  float* out = (float*)d_out;

  float* ws     = (float*)d_ws;
  float* attn   = ws;                                 // B*S*K = 655360 f
  float* ws2    = attn + (size_t)BB * SS * KK;        // B*K*D = 40960 f
  float* params = ws2 + (size_t)BB * KK * DD;         // 64 f
  float* Mpart  = params + 64;

  size_t head_f = (size_t)BB * SS * KK + (size_t)BB * KK * DD + 64;
  int cpb = 256, tpc = 32;                            // preferred: 1024 scatter blocks
  size_t need = (head_f + (size_t)BB * cpb * KK * DD) * sizeof(float);  // ~44.7 MB
  if (ws_size < need) { cpb = 128; tpc = 64; }        // ~23.8 MB (R3-proven)

  k0_params<<<KK, 64, 0, stream>>>(pos, ls, am, params);
  kA_attn<<<1024, 256, 0, stream>>>(x, pos, params, attn);
  kB_scatter<<<dim3(cpb, BB), 256, 0, stream>>>(x, attn, Mpart, tpc);
  k3f<<<BB * KK, 512, 0, stream>>>(Mpart, w_v, w_o, ws2, cpb);
  k5_gather<<<2048, 256, 0, stream>>>(attn, ws2, out);
}